// Round 1
// baseline (736.235 us; speedup 1.0000x reference)
//
#include <hip/hip_runtime.h>

// FluxSingleAttention on MI355X (gfx950)
// Stages: [1] hs f32->bf16  [2] w_qkv transpose->bf16 [N][K]
//         [3] MFMA GEMM qkv = hs@W + b  -> qkv bf16 [3][B][H][S][D]
//         [4] RMSNorm+RoPE on q,k in place
//         [5] V transpose -> Vt [B][H][D][S]
//         [6] flash attention -> out f32 [B,S,H*D]
// ws layout (bytes): A_bf 0..25165824 | Wt ..81788928 | qkv ..157286400 | Vt ..182452224

#define SS 2048
#define BB 2
#define HH 24
#define DD 128
#define KDIM 3072
#define N3 9216
#define MM 4096

typedef float f32x4 __attribute__((ext_vector_type(4)));
typedef __bf16 bf16x8 __attribute__((ext_vector_type(8)));

__device__ __forceinline__ unsigned short f2b(float f) {
  union { float f; unsigned int u; } v; v.f = f;
  unsigned int u = v.u;
  u += 0x7FFFu + ((u >> 16) & 1u);   // RNE
  return (unsigned short)(u >> 16);
}
__device__ __forceinline__ float b2f(unsigned short b) {
  union { unsigned int u; float f; } v; v.u = ((unsigned int)b) << 16; return v.f;
}
__device__ __forceinline__ f32x4 mfma16(bf16x8 a, bf16x8 b, f32x4 c) {
  return __builtin_amdgcn_mfma_f32_16x16x32_bf16(a, b, c, 0, 0, 0);
}
typedef __attribute__((address_space(1))) void gas_void;
typedef __attribute__((address_space(3))) void las_void;
__device__ __forceinline__ void load_lds16(const void* g, void* l) {
  __builtin_amdgcn_global_load_lds((gas_void*)g, (las_void*)l, 16, 0, 0);
}
// XOR swizzle: spreads 16-way same-bank rows across 8 16B slots (free 2-way)
__device__ __forceinline__ int swz(int row, int byteInRow) {
  return byteInRow ^ ((row & 7) << 4);
}

// ---------------- [1] f32 -> bf16 convert ----------------
__global__ void cvt_bf16(const float* __restrict__ in, unsigned short* __restrict__ out, int n4) {
  int i = blockIdx.x * 256 + threadIdx.x;
  if (i >= n4) return;
  float4 v = reinterpret_cast<const float4*>(in)[i];
  ushort4 o;
  o.x = f2b(v.x); o.y = f2b(v.y); o.z = f2b(v.z); o.w = f2b(v.w);
  reinterpret_cast<ushort4*>(out)[i] = o;
}

// ---------------- [2] W [K][N] f32 -> Wt [N][K] bf16 ----------------
__global__ void transpose_w(const float* __restrict__ w, unsigned short* __restrict__ wt) {
  __shared__ float tile[32][33];
  int n0 = blockIdx.x * 32, k0 = blockIdx.y * 32;
  int tx = threadIdx.x, ty = threadIdx.y;  // (32,8)
#pragma unroll
  for (int i = 0; i < 4; i++)
    tile[ty + 8 * i][tx] = w[(size_t)(k0 + ty + 8 * i) * N3 + n0 + tx];
  __syncthreads();
#pragma unroll
  for (int i = 0; i < 4; i++)
    wt[(size_t)(n0 + ty + 8 * i) * KDIM + k0 + tx] = f2b(tile[tx][ty + 8 * i]);
}

// ---------------- [3] GEMM: qkv = A @ Wt^T + bias ----------------
// A [4096][3072] bf16, Wt [9216][3072] bf16. 128x128 tile, BK=64, 4 waves (2x2),
// wave = 64x64 out = 4x4 16x16x32 MFMA frags. global_load_lds width 16, linear LDS.
__global__ __launch_bounds__(256, 2) void gemm_qkv(
    const unsigned short* __restrict__ A, const unsigned short* __restrict__ Bt,
    const float* __restrict__ bias, unsigned short* __restrict__ qkv) {
  __shared__ __align__(16) unsigned short As[128 * 64];
  __shared__ __align__(16) unsigned short Bs[128 * 64];
  const int tid = threadIdx.x;
  const int wave = tid >> 6, lane = tid & 63;
  const int wm = wave >> 1, wn = wave & 1;
  const int g = lane >> 4, lr = lane & 15;
  const int m0 = blockIdx.x * 128, n0 = blockIdx.y * 128;

  f32x4 acc[4][4] = {};

  for (int k0 = 0; k0 < KDIM; k0 += 64) {
    __syncthreads();  // protect LDS from prev-iter readers
#pragma unroll
    for (int i = 0; i < 4; i++) {
      int c = wave * 4 + i;                    // 1KB chunk: 8 rows of 64 bf16
      int row = c * 8 + (lane >> 3);
      int kk = (lane & 7) * 8;
      load_lds16(A + (size_t)(m0 + row) * KDIM + k0 + kk, &As[c * 512]);
      load_lds16(Bt + (size_t)(n0 + row) * KDIM + k0 + kk, &Bs[c * 512]);
    }
    __syncthreads();
#pragma unroll
    for (int kk = 0; kk < 64; kk += 32) {
      bf16x8 af[4], bfr[4];
#pragma unroll
      for (int i = 0; i < 4; i++) {
        af[i]  = *reinterpret_cast<const bf16x8*>(&As[(wm * 64 + i * 16 + lr) * 64 + kk + g * 8]);
        bfr[i] = *reinterpret_cast<const bf16x8*>(&Bs[(wn * 64 + i * 16 + lr) * 64 + kk + g * 8]);
      }
#pragma unroll
      for (int i = 0; i < 4; i++)
#pragma unroll
        for (int j = 0; j < 4; j++)
          acc[i][j] = mfma16(af[i], bfr[j], acc[i][j]);
    }
  }

  // epilogue: block's 128 cols = exactly one (which, head) slice
  const int which = n0 / 3072;
  const int h = (n0 % 3072) / 128;
#pragma unroll
  for (int bj = 0; bj < 4; bj++) {
    int d = wn * 64 + bj * 16 + lr;
    float bv = bias[n0 + d];
#pragma unroll
    for (int ai = 0; ai < 4; ai++) {
#pragma unroll
      for (int r = 0; r < 4; r++) {
        int m = m0 + wm * 64 + ai * 16 + g * 4 + r;
        int b = m >> 11, s = m & 2047;
        float val = acc[ai][bj][r] + bv;
        qkv[((((size_t)which * BB + b) * HH + h) * SS + s) * DD + d] = f2b(val);
      }
    }
  }
}

// ---------------- [4] RMSNorm + RoPE on q,k (in place) ----------------
// one wave per (which,b,h,s) row; lane = rotary pair p (D/2 = 64 = wave size)
__global__ void rms_rope(unsigned short* qkv, const float* __restrict__ freqs,
                         const float* __restrict__ wq, const float* __restrict__ wk) {
  int row = blockIdx.x * 4 + (threadIdx.x >> 6);
  int lane = threadIdx.x & 63;
  int s = row & 2047;
  int t = row >> 11;                 // which*48 + b*24 + h
  int which = t / (BB * HH);
  unsigned short* x = qkv + (size_t)row * DD;
  ushort2 xx = *reinterpret_cast<ushort2*>(&x[lane * 2]);
  float x0 = b2f(xx.x), x1 = b2f(xx.y);
  float ssum = x0 * x0 + x1 * x1;
#pragma unroll
  for (int off = 1; off < 64; off <<= 1) ssum += __shfl_xor(ssum, off);
  float rn = rsqrtf(ssum * (1.0f / 128.0f) + 1e-6f);
  const float* wgt = which ? wk : wq;
  x0 *= rn * wgt[lane * 2];
  x1 *= rn * wgt[lane * 2 + 1];
  float4 f = reinterpret_cast<const float4*>(freqs)[s * 64 + lane];  // f00,f01,f10,f11
  ushort2 yy;
  yy.x = f2b(f.x * x0 + f.y * x1);
  yy.y = f2b(f.z * x0 + f.w * x1);
  *reinterpret_cast<ushort2*>(&x[lane * 2]) = yy;
}

// ---------------- [5] V [S][D] -> Vt [D][S] per (b,h) ----------------
__global__ void transpose_v(const unsigned short* __restrict__ qkv, unsigned short* __restrict__ vt) {
  __shared__ unsigned short tile[32][33];
  int bh = blockIdx.z;
  int s0 = blockIdx.x * 32, d0 = blockIdx.y * 32;
  const unsigned short* v = qkv + ((size_t)2 * BB * HH + bh) * SS * DD;
  int tx = threadIdx.x, ty = threadIdx.y;  // (32,8)
#pragma unroll
  for (int i = 0; i < 4; i++)
    tile[ty + 8 * i][tx] = v[(size_t)(s0 + ty + 8 * i) * DD + d0 + tx];
  __syncthreads();
  unsigned short* o = vt + (size_t)bh * DD * SS;
#pragma unroll
  for (int i = 0; i < 4; i++)
    o[(size_t)(d0 + ty + 8 * i) * SS + s0 + tx] = tile[tx][ty + 8 * i];
}

// ---------------- [6] flash attention ----------------
// grid (S/64, B*H); 4 waves x 16 q-rows. KV tile = 64. K/V staged via
// global_load_lds with pre-swizzled SOURCE (LDS write is linear; read applies
// the same XOR) -> conflict-free ds_read_b128. P via swizzled per-wave LDS.
__global__ __launch_bounds__(256, 2) void attn(
    const unsigned short* __restrict__ qkv, const unsigned short* __restrict__ vt,
    float* __restrict__ out) {
  __shared__ __align__(16) unsigned short Ks[64 * 128];   // [kr][d], 256B rows, swizzled
  __shared__ __align__(16) unsigned short Vs[128 * 64];   // [d][kr], 128B rows, swizzled
  __shared__ __align__(16) unsigned short Ps[4][16 * 64]; // per-wave P, 128B rows, swizzled
  const int bh = blockIdx.y;
  const int q0 = blockIdx.x * 64;
  const int wave = threadIdx.x >> 6, lane = threadIdx.x & 63;
  const int g = lane >> 4, lr = lane & 15;
  const unsigned short* Q   = qkv + (size_t)bh * SS * DD;
  const unsigned short* Kp  = qkv + ((size_t)BB * HH + bh) * SS * DD;
  const unsigned short* Vtp = vt + (size_t)bh * DD * SS;

  bf16x8 qf[4];
  {
    int qr = q0 + wave * 16 + lr;
#pragma unroll
    for (int kd = 0; kd < 4; kd++)
      qf[kd] = *reinterpret_cast<const bf16x8*>(&Q[(size_t)qr * DD + kd * 32 + g * 8]);
  }
  float mrow[4], lrow[4];
  f32x4 o[8] = {};
#pragma unroll
  for (int r = 0; r < 4; r++) { mrow[r] = -1e30f; lrow[r] = 0.f; }
  const float scale = 0.08838834764831845f;  // 1/sqrt(128)

  for (int kt = 0; kt < SS / 64; kt++) {
    int k0 = kt * 64;
    __syncthreads();
#pragma unroll
    for (int i = 0; i < 4; i++) {
      int c = wave * 4 + i;
      {  // K chunk: 4 rows of 256B
        int row = c * 4 + g;
        int lb = swz(row, lr * 16);
        load_lds16(Kp + (size_t)(k0 + row) * DD + (lb >> 1), &Ks[c * 512]);
      }
      {  // V chunk: 8 rows of 128B
        int row = c * 8 + (lane >> 3);
        int lb = swz(row, (lane & 7) * 16);
        load_lds16(Vtp + (size_t)row * SS + k0 + (lb >> 1), &Vs[c * 512]);
      }
    }
    __syncthreads();

    // S = Q K^T
    f32x4 sc[4] = {};
#pragma unroll
    for (int cf = 0; cf < 4; cf++) {
#pragma unroll
      for (int kd = 0; kd < 4; kd++) {
        int row = cf * 16 + lr;
        bf16x8 kb = *reinterpret_cast<const bf16x8*>(
            &Ks[(row * 256 + swz(row, kd * 64 + g * 16)) >> 1]);
        sc[cf] = mfma16(qf[kd], kb, sc[cf]);
      }
    }
#pragma unroll
    for (int cf = 0; cf < 4; cf++) sc[cf] *= scale;

    // online softmax (rows: 16 lanes of same group share a row)
#pragma unroll
    for (int r = 0; r < 4; r++) {
      float pm = fmaxf(fmaxf(sc[0][r], sc[1][r]), fmaxf(sc[2][r], sc[3][r]));
      pm = fmaxf(pm, __shfl_xor(pm, 1));
      pm = fmaxf(pm, __shfl_xor(pm, 2));
      pm = fmaxf(pm, __shfl_xor(pm, 4));
      pm = fmaxf(pm, __shfl_xor(pm, 8));
      float mnew = fmaxf(mrow[r], pm);
      float corr = __expf(mrow[r] - mnew);
      float psum = 0.f;
      int prow = g * 4 + r;
#pragma unroll
      for (int cf = 0; cf < 4; cf++) {
        float p = __expf(sc[cf][r] - mnew);
        psum += p;
        int col = cf * 16 + lr;
        Ps[wave][(prow * 128 + swz(prow, col * 2)) >> 1] = f2b(p);
      }
      psum += __shfl_xor(psum, 1);
      psum += __shfl_xor(psum, 2);
      psum += __shfl_xor(psum, 4);
      psum += __shfl_xor(psum, 8);
      lrow[r] = lrow[r] * corr + psum;
      mrow[r] = mnew;
#pragma unroll
      for (int dn = 0; dn < 8; dn++) o[dn][r] *= corr;
    }

    // O += P V   (same-wave LDS write->read: DS pipe is in-order per wave)
#pragma unroll
    for (int ks = 0; ks < 2; ks++) {
      bf16x8 pa = *reinterpret_cast<const bf16x8*>(
          &Ps[wave][(lr * 128 + swz(lr, ks * 64 + g * 16)) >> 1]);
#pragma unroll
      for (int dn = 0; dn < 8; dn++) {
        int vrow = dn * 16 + lr;
        bf16x8 vb = *reinterpret_cast<const bf16x8*>(
            &Vs[(vrow * 128 + swz(vrow, ks * 64 + g * 16)) >> 1]);
        o[dn] = mfma16(pa, vb, o[dn]);
      }
    }
  }

  const int b = bh / HH, h = bh % HH;
#pragma unroll
  for (int r = 0; r < 4; r++) {
    int s = q0 + wave * 16 + g * 4 + r;
    float inv = 1.0f / lrow[r];
#pragma unroll
    for (int dn = 0; dn < 8; dn++) {
      int d = dn * 16 + lr;
      out[((size_t)b * SS + s) * 3072 + h * DD + d] = o[dn][r] * inv;
    }
  }
}

extern "C" void kernel_launch(void* const* d_in, const int* in_sizes, int n_in,
                              void* d_out, int out_size, void* d_ws, size_t ws_size,
                              hipStream_t stream) {
  const float* hs     = (const float*)d_in[0];
  const float* freqs  = (const float*)d_in[1];
  const float* w_qkv  = (const float*)d_in[2];
  const float* b_qkv  = (const float*)d_in[3];
  const float* norm_q = (const float*)d_in[4];
  const float* norm_k = (const float*)d_in[5];
  float* out = (float*)d_out;

  char* ws = (char*)d_ws;
  unsigned short* A_bf = (unsigned short*)(ws);                         // 25165824 B
  unsigned short* Wt   = (unsigned short*)(ws + 25165824);              // 56623104 B
  unsigned short* qkv  = (unsigned short*)(ws + 81788928);              // 75497472 B
  unsigned short* Vt   = (unsigned short*)(ws + 157286400);             // 25165824 B

  cvt_bf16<<<dim3(12288), dim3(256), 0, stream>>>(hs, A_bf, 3145728);
  transpose_w<<<dim3(288, 96), dim3(32, 8), 0, stream>>>(w_qkv, Wt);
  gemm_qkv<<<dim3(32, 72), dim3(256), 0, stream>>>(A_bf, Wt, b_qkv, qkv);
  rms_rope<<<dim3(49152), dim3(256), 0, stream>>>(qkv, freqs, norm_q, norm_k);
  transpose_v<<<dim3(64, 4, 48), dim3(32, 8), 0, stream>>>(qkv, Vt);
  attn<<<dim3(32, 48), dim3(256), 0, stream>>>(qkv, Vt, out);
}